// Round 5
// baseline (484.949 us; speedup 1.0000x reference)
//
#include <hip/hip_runtime.h>
#include <hip/hip_bf16.h>
#include <math.h>

// ExpertPool: B=2,N=1024 -> T=2048 tokens, D=768, E=8, H=3072, top-K=2
#define T_TOK 2048
#define DIM   768
#define NEXP  8
#define HDIM  3072
#define MAXP  (T_TOK * 2)   // exactly 4096 (token,expert) pairs
#define LDST  40            // LDS row stride in ushorts (80 B)
#define NT64_MAX  72        // sum ceil(cnt_e/64)  <= 4096/64 + 8 = 72 (gv tiles)
#define NT128_MAX 40        // sum ceil(cnt_e/128) <= 39          (out tiles)

typedef __attribute__((ext_vector_type(8))) short bfrag;   // 8 bf16 (4 VGPRs)
typedef __attribute__((ext_vector_type(4))) float f32x4;   // MFMA C/D

__device__ __forceinline__ unsigned short f2bf(float f) {
  union { float f; unsigned int u; } x; x.f = f;
  unsigned int r = x.u + 0x7fffu + ((x.u >> 16) & 1u);  // RNE
  return (unsigned short)(r >> 16);
}

// ---------------- routing + tile tables + token->pair map ----------------
// meta: [0..7]=cnt [8..15]=off [16]=nt64 [17..88]=tiles64 [89]=nt128 [90..129]=tiles128
__global__ void k_route(const float* __restrict__ disp,
                        const float* __restrict__ comb,
                        int* __restrict__ meta,
                        float* __restrict__ row_comb,
                        int* __restrict__ row_token,
                        int* __restrict__ tok2pair) {  // (T_TOK,2)
  __shared__ int s_cnt[NEXP], s_off[NEXP], s_cur[NEXP];
  __shared__ int s_tn[T_TOK];
  int tid = threadIdx.x;
  if (tid < NEXP) s_cnt[tid] = 0;
  for (int t = tid; t < T_TOK; t += 256) s_tn[t] = 0;
  __syncthreads();
  for (int t = tid; t < T_TOK; t += 256)
    for (int e = 0; e < NEXP; ++e)
      if (disp[t * NEXP + e] > 0.f) atomicAdd(&s_cnt[e], 1);
  __syncthreads();
  if (tid == 0) {
    int acc = 0;
    for (int e = 0; e < NEXP; ++e) { s_off[e] = acc; acc += s_cnt[e]; }
  }
  __syncthreads();
  if (tid < NEXP) {
    s_cur[tid] = s_off[tid];
    meta[tid] = s_cnt[tid];
    meta[NEXP + tid] = s_off[tid];
  }
  __syncthreads();
  for (int t = tid; t < T_TOK; t += 256)
    for (int e = 0; e < NEXP; ++e)
      if (disp[t * NEXP + e] > 0.f) {
        int p = atomicAdd(&s_cur[e], 1);
        row_token[p] = t;
        row_comb[p] = comb[t * NEXP + e];
        int sl = atomicAdd(&s_tn[t], 1);
        tok2pair[t * 2 + sl] = p;
      }
  __syncthreads();
  if (tid == 0) {
    int nt = 0;
    for (int e = 0; e < NEXP; ++e)
      for (int m0 = 0; m0 < s_cnt[e]; m0 += 64)
        meta[17 + nt++] = (e << 16) | (m0 >> 6);
    meta[16] = nt;
    int nt2 = 0;
    for (int e = 0; e < NEXP; ++e)
      for (int m0 = 0; m0 < s_cnt[e]; m0 += 128)
        meta[90 + nt2++] = (e << 16) | (m0 >> 7);
    meta[89] = nt2;
  }
}

// ---------------- X -> bf16 once (3 MB) ----------------
__global__ void k_xbf(const float* __restrict__ X, unsigned short* __restrict__ Xb) {
  size_t i = ((size_t)blockIdx.x * 256 + threadIdx.x) * 8;
  float4 a = *(const float4*)(X + i);
  float4 b = *(const float4*)(X + i + 4);
  unsigned short r[8];
  r[0]=f2bf(a.x); r[1]=f2bf(a.y); r[2]=f2bf(a.z); r[3]=f2bf(a.w);
  r[4]=f2bf(b.x); r[5]=f2bf(b.y); r[6]=f2bf(b.z); r[7]=f2bf(b.w);
  *(uint4*)(Xb + i) = *(uint4*)r;
}

// ------- GEMM 1 fused: u = gelu(X@Wg^T) * (X@Wv^T) -> bf16 (P,H) -------
// 64x128 tiles (acc=64 regs/wave) + register prefetch of next k-step's
// global loads (issued before MFMA -> latency hides under compute).
// Strip-affinity XCD remap kept from r4 (FETCH 338->102 MB proven).
__global__ __launch_bounds__(256, 2) void k_gemm_gv(
    const unsigned short* __restrict__ Xb,  // (T_TOK, DIM) bf16
    const float* __restrict__ Wg,           // (NEXP, HDIM, DIM)
    const float* __restrict__ Wv,
    const int* __restrict__ meta,
    const int* __restrict__ row_token,
    unsigned short* __restrict__ ubuf)      // (MAXP, HDIM) bf16
{
  int blk = blockIdx.x;                     // 1728 = 8 xcd * 3 strips * 72 tiles
  int c = blk & 7, slot = blk >> 3;         // xcd id, 216 slots per xcd
  int nt = c + 8 * (slot / NT64_MAX);       // n-strip pinned to xcd c
  int t  = slot % NT64_MAX;                 // tile slot iterates fastest
  if (t >= meta[16]) return;
  int tv = meta[17 + t];
  int e = tv >> 16, m0 = (tv & 0xffff) << 6;
  int cnt = meta[e], off = meta[NEXP + e];
  int n0 = nt * 128;

  __shared__ unsigned short As[64 * LDST];
  __shared__ unsigned short Bgs[128 * LDST];
  __shared__ unsigned short Bvs[128 * LDST];

  int tid = threadIdx.x;
  int wid = tid >> 6, lane = tid & 63;
  int wm = (wid >> 1) * 32, wn = (wid & 1) * 64;
  int lr = lane & 15, quad = lane >> 4;

  // A gather: 64 rows x 4 16B-chunks = 256 chunks -> 1 per thread
  int arow = tid >> 2, asub = tid & 3;
  int atok;
  { int gr = m0 + arow; if (gr >= cnt) gr = cnt - 1;
    atok = row_token[off + gr]; }

  const float* Wgb = Wg + (size_t)e * ((size_t)HDIM * DIM);
  const float* Wvb = Wv + (size_t)e * ((size_t)HDIM * DIM);

  // B stage: 128 rows x 8 float4-chunks = 1024 -> 4 rounds
  int brow[4], bc4[4];
#pragma unroll
  for (int r = 0; r < 4; ++r) { int c2 = tid + 256 * r; brow[r] = c2 >> 3; bc4[r] = c2 & 7; }

  f32x4 zero4 = {0.f, 0.f, 0.f, 0.f};
  f32x4 accg[2][4], accv[2][4];
#pragma unroll
  for (int i = 0; i < 2; ++i)
#pragma unroll
    for (int j = 0; j < 4; ++j) { accg[i][j] = zero4; accv[i][j] = zero4; }

  // prefetch registers (single set: consumed by LDS-write before reissue)
  uint4 aR;
  float4 gR[4], vR[4];

  // prologue: issue k0=0 loads
  aR = *(const uint4*)(Xb + (size_t)atok * DIM + asub * 8);
#pragma unroll
  for (int r = 0; r < 4; ++r) {
    gR[r] = *(const float4*)(Wgb + (size_t)(n0 + brow[r]) * DIM + bc4[r] * 4);
    vR[r] = *(const float4*)(Wvb + (size_t)(n0 + brow[r]) * DIM + bc4[r] * 4);
  }

  for (int k0 = 0; k0 < DIM; k0 += 32) {
    __syncthreads();                       // prev iter's ds_reads done
    *(uint4*)(&As[arow * LDST + asub * 8]) = aR;
#pragma unroll
    for (int r = 0; r < 4; ++r) {
      ushort4 gp;
      gp.x = f2bf(gR[r].x); gp.y = f2bf(gR[r].y); gp.z = f2bf(gR[r].z); gp.w = f2bf(gR[r].w);
      *(ushort4*)(&Bgs[brow[r] * LDST + bc4[r] * 4]) = gp;
      ushort4 vp;
      vp.x = f2bf(vR[r].x); vp.y = f2bf(vR[r].y); vp.z = f2bf(vR[r].z); vp.w = f2bf(vR[r].w);
      *(ushort4*)(&Bvs[brow[r] * LDST + bc4[r] * 4]) = vp;
    }
    int kn = k0 + 32;
    if (kn < DIM) {                        // issue NEXT iter's loads now;
      aR = *(const uint4*)(Xb + (size_t)atok * DIM + kn + asub * 8);
#pragma unroll
      for (int r = 0; r < 4; ++r) {        // latency hides under MFMA below
        gR[r] = *(const float4*)(Wgb + (size_t)(n0 + brow[r]) * DIM + kn + bc4[r] * 4);
        vR[r] = *(const float4*)(Wvb + (size_t)(n0 + brow[r]) * DIM + kn + bc4[r] * 4);
      }
    }
    __syncthreads();                       // LDS tile ready
    bfrag a[2], bg[4], bv[4];
#pragma unroll
    for (int i = 0; i < 2; ++i)
      a[i] = *(const bfrag*)(&As[(wm + i * 16 + lr) * LDST + quad * 8]);
#pragma unroll
    for (int j = 0; j < 4; ++j) {
      bg[j] = *(const bfrag*)(&Bgs[(wn + j * 16 + lr) * LDST + quad * 8]);
      bv[j] = *(const bfrag*)(&Bvs[(wn + j * 16 + lr) * LDST + quad * 8]);
    }
#pragma unroll
    for (int i = 0; i < 2; ++i)
#pragma unroll
      for (int j = 0; j < 4; ++j) {
        accg[i][j] = __builtin_amdgcn_mfma_f32_16x16x32_bf16(a[i], bg[j], accg[i][j], 0, 0, 0);
        accv[i][j] = __builtin_amdgcn_mfma_f32_16x16x32_bf16(a[i], bv[j], accv[i][j], 0, 0, 0);
      }
  }

  // epilogue: gelu_exact(g)*v on fp32 accumulators
#pragma unroll
  for (int i = 0; i < 2; ++i)
#pragma unroll
    for (int rg = 0; rg < 4; ++rg) {
      int gr = m0 + wm + i * 16 + quad * 4 + rg;
      if (gr < cnt) {
        size_t base = (size_t)(off + gr) * HDIM + n0 + wn;
#pragma unroll
        for (int j = 0; j < 4; ++j) {
          float g = accg[i][j][rg];
          float v = accv[i][j][rg];
          float u = 0.5f * g * (1.0f + erff(g * 0.70710678118654752f)) * v;
          ubuf[base + j * 16 + lr] = f2bf(u);
        }
      }
    }
}

// ------- GEMM 2: u @ Wo^T, split-K x4, 128x128 tiles + register prefetch.
//         mode 0: store w-scaled partials; mode 1: atomicAdd fallback. -------
__global__ __launch_bounds__(256, 2) void k_gemm_out(
    const unsigned short* __restrict__ U,  // (MAXP, HDIM) bf16
    const float* __restrict__ Wo,          // (NEXP, DIM, HDIM)
    const float* __restrict__ scale,
    const int* __restrict__ meta,
    const int* __restrict__ row_token,
    const float* __restrict__ row_comb,
    float* __restrict__ partial,           // (4, MAXP, DIM)
    float* __restrict__ out,               // (T_TOK, DIM)
    int mode)
{
  int blk = blockIdx.x;                    // 960 = 8 xcd * 3 strips * 40 tiles
  int c = blk & 7, slot = blk >> 3;
  int sidx = c + 8 * (slot / NT128_MAX);   // 0..23 strip index = (nt, ks)
  int nt = sidx % 6, ks = sidx / 6;
  int t = slot % NT128_MAX;
  if (t >= meta[89]) return;
  int tv = meta[90 + t];
  int e = tv >> 16, m0 = (tv & 0xffff) << 7;
  int cnt = meta[e], off = meta[NEXP + e];
  int n0 = nt * 128;
  int kbase = ks * (HDIM / 4);

  __shared__ unsigned short As[128 * LDST];
  __shared__ unsigned short Bs[128 * LDST];

  int tid = threadIdx.x;
  int wid = tid >> 6, lane = tid & 63;
  int wm = (wid >> 1) * 64, wn = (wid & 1) * 64;
  int lr = lane & 15, quad = lane >> 4;

  int a_grow[2];
#pragma unroll
  for (int r = 0; r < 2; ++r) {
    int row = (tid + 256 * r) >> 2;
    int gr = m0 + row; if (gr >= cnt) gr = cnt - 1;
    a_grow[r] = off + gr;
  }
  int asub = tid & 3;

  const float* Wb = Wo + (size_t)e * ((size_t)DIM * HDIM);

  int brow[4], bc4[4];
#pragma unroll
  for (int r = 0; r < 4; ++r) { int c2 = tid + 256 * r; brow[r] = c2 >> 3; bc4[r] = c2 & 7; }

  f32x4 zero4 = {0.f, 0.f, 0.f, 0.f};
  f32x4 acc[4][4];
#pragma unroll
  for (int i = 0; i < 4; ++i)
#pragma unroll
    for (int j = 0; j < 4; ++j) acc[i][j] = zero4;

  uint4 aR[2];
  float4 bR[4];

  // prologue: issue k=kbase loads
#pragma unroll
  for (int r = 0; r < 2; ++r)
    aR[r] = *(const uint4*)(U + (size_t)a_grow[r] * HDIM + kbase + asub * 8);
#pragma unroll
  for (int r = 0; r < 4; ++r)
    bR[r] = *(const float4*)(Wb + (size_t)(n0 + brow[r]) * HDIM + kbase + bc4[r] * 4);

  for (int kk = 0; kk < HDIM / 4; kk += 32) {
    int k0 = kbase + kk;
    __syncthreads();
#pragma unroll
    for (int r = 0; r < 2; ++r) {
      int row = (tid + 256 * r) >> 2;
      *(uint4*)(&As[row * LDST + asub * 8]) = aR[r];
    }
#pragma unroll
    for (int r = 0; r < 4; ++r) {
      ushort4 bp;
      bp.x = f2bf(bR[r].x); bp.y = f2bf(bR[r].y); bp.z = f2bf(bR[r].z); bp.w = f2bf(bR[r].w);
      *(ushort4*)(&Bs[brow[r] * LDST + bc4[r] * 4]) = bp;
    }
    int kn = k0 + 32;
    if (kk + 32 < HDIM / 4) {
#pragma unroll
      for (int r = 0; r < 2; ++r)
        aR[r] = *(const uint4*)(U + (size_t)a_grow[r] * HDIM + kn + asub * 8);
#pragma unroll
      for (int r = 0; r < 4; ++r)
        bR[r] = *(const float4*)(Wb + (size_t)(n0 + brow[r]) * HDIM + kn + bc4[r] * 4);
    }
    __syncthreads();
    bfrag a[4], b[4];
#pragma unroll
    for (int i = 0; i < 4; ++i)
      a[i] = *(const bfrag*)(&As[(wm + i * 16 + lr) * LDST + quad * 8]);
#pragma unroll
    for (int j = 0; j < 4; ++j)
      b[j] = *(const bfrag*)(&Bs[(wn + j * 16 + lr) * LDST + quad * 8]);
#pragma unroll
    for (int i = 0; i < 4; ++i)
#pragma unroll
      for (int j = 0; j < 4; ++j)
        acc[i][j] = __builtin_amdgcn_mfma_f32_16x16x32_bf16(a[i], b[j], acc[i][j], 0, 0, 0);
  }

  float sc = scale[e];
#pragma unroll
  for (int i = 0; i < 4; ++i)
#pragma unroll
    for (int rg = 0; rg < 4; ++rg) {
      int gr = m0 + wm + i * 16 + quad * 4 + rg;
      if (gr < cnt) {
        int grow = off + gr;
        float w = row_comb[grow] * sc;
        if (mode == 0) {
          float* pb = partial + ((size_t)ks * MAXP + grow) * DIM + n0 + wn;
#pragma unroll
          for (int j = 0; j < 4; ++j)
            pb[j * 16 + lr] = acc[i][j][rg] * w;
        } else {
          int tok = row_token[grow];
          float* ob = out + (size_t)tok * DIM + n0 + wn;
#pragma unroll
          for (int j = 0; j < 4; ++j)
            atomicAdd(ob + j * 16 + lr, acc[i][j][rg] * w);
        }
      }
    }
}

// ---------------- combine: out[t] = sum over 2 pairs x 4 K-splits ----------------
__global__ void k_combine(const float* __restrict__ partial,
                          const int* __restrict__ tok2pair,
                          float* __restrict__ out) {
  int idx = blockIdx.x * 256 + threadIdx.x;   // 2048 * 192 = 393216
  int t = idx / 192, d4 = idx % 192;
  int p0 = tok2pair[t * 2], p1 = tok2pair[t * 2 + 1];
  float sx = 0.f, sy = 0.f, sz = 0.f, sw = 0.f;
#pragma unroll
  for (int ks = 0; ks < 4; ++ks) {
    float4 a = *(const float4*)(partial + ((size_t)ks * MAXP + p0) * DIM + d4 * 4);
    float4 b = *(const float4*)(partial + ((size_t)ks * MAXP + p1) * DIM + d4 * 4);
    sx += a.x + b.x; sy += a.y + b.y; sz += a.z + b.z; sw += a.w + b.w;
  }
  float4 r; r.x = sx; r.y = sy; r.z = sz; r.w = sw;
  *(float4*)(out + (size_t)t * DIM + d4 * 4) = r;
}

extern "C" void kernel_launch(void* const* d_in, const int* in_sizes, int n_in,
                              void* d_out, int out_size, void* d_ws, size_t ws_size,
                              hipStream_t stream) {
  const float* tokens = (const float*)d_in[0];
  const float* disp   = (const float*)d_in[1];
  const float* comb   = (const float*)d_in[2];
  const float* Wg     = (const float*)d_in[3];
  const float* Wv     = (const float*)d_in[4];
  const float* Wo     = (const float*)d_in[5];
  const float* scale  = (const float*)d_in[6];
  float* out = (float*)d_out;

  char* ws = (char*)d_ws;
  int*   meta      = (int*)ws;                        // 130 ints
  int*   row_token = (int*)(ws + 16384);
  float* row_comb  = (float*)(ws + 32768);
  int*   tok2pair  = (int*)(ws + 49152);
  unsigned short* Xb   = (unsigned short*)(ws + (1u << 20));            // 3 MB
  unsigned short* ubuf = (unsigned short*)(ws + (5u << 20));            // 24 MB
  float* partial = (float*)(ws + (32ull << 20));                        // 48 MB
  size_t need_partial = (32ull << 20) + (size_t)4 * MAXP * DIM * sizeof(float);
  int mode = (ws_size >= need_partial) ? 0 : 1;

  hipLaunchKernelGGL(k_route, dim3(1), dim3(256), 0, stream,
                     disp, comb, meta, row_comb, row_token, tok2pair);
  hipLaunchKernelGGL(k_xbf, dim3((T_TOK * DIM) / (256 * 8)), dim3(256), 0, stream,
                     tokens, Xb);
  hipLaunchKernelGGL(k_gemm_gv, dim3(NT64_MAX * 24), dim3(256), 0, stream,
                     Xb, Wg, Wv, meta, row_token, ubuf);
  if (mode == 1)
    hipMemsetAsync(d_out, 0, (size_t)out_size * sizeof(float), stream);
  hipLaunchKernelGGL(k_gemm_out, dim3(NT128_MAX * 6 * 4), dim3(256), 0, stream,
                     ubuf, Wo, scale, meta, row_token, row_comb, partial, out, mode);
  if (mode == 0)
    hipLaunchKernelGGL(k_combine, dim3((T_TOK * DIM / 4) / 256), dim3(256), 0, stream,
                       partial, tok2pair, out);
}

// Round 6
// 402.835 us; speedup vs baseline: 1.2038x; 1.2038x over previous
//
#include <hip/hip_runtime.h>
#include <hip/hip_bf16.h>
#include <math.h>

// ExpertPool: B=2,N=1024 -> T=2048 tokens, D=768, E=8, H=3072, top-K=2
#define T_TOK 2048
#define DIM   768
#define NEXP  8
#define HDIM  3072
#define MAXP  (T_TOK * 2)   // exactly 4096 (token,expert) pairs
#define LDST  40            // LDS row stride in ushorts (80 B)
#define NTILE_MAX 40        // sum ceil(cnt_e/128) <= 39

typedef __attribute__((ext_vector_type(8))) short bfrag;   // 8 bf16 (4 VGPRs)
typedef __attribute__((ext_vector_type(4))) float f32x4;   // MFMA C/D

__device__ __forceinline__ unsigned short f2bf(float f) {
  union { float f; unsigned int u; } x; x.f = f;
  unsigned int r = x.u + 0x7fffu + ((x.u >> 16) & 1u);  // RNE
  return (unsigned short)(r >> 16);
}

// ---- fused prep: block 0 = routing; all other blocks = fp32->bf16 streaming
//      conversion of X (768 blks), Wg/Wv/Wo (3 x 9216 blks, if wbf).
//      Routing (~25us, previously serial with GPU idle) hides under the
//      ~60us conversion stream; two launch gaps removed.
__global__ void k_prep(const float* __restrict__ disp,
                       const float* __restrict__ comb,
                       int* __restrict__ meta,        // [0..7]=cnt [8..15]=off [16]=ntiles [17..56]=tiles
                       float* __restrict__ row_comb,
                       int* __restrict__ row_token,
                       int* __restrict__ tok2pair,    // (T_TOK,2)
                       const float* __restrict__ X, unsigned short* __restrict__ Xb,
                       const float* __restrict__ Wg, const float* __restrict__ Wv,
                       const float* __restrict__ Wo,
                       unsigned short* __restrict__ Wgh, unsigned short* __restrict__ Wvh,
                       unsigned short* __restrict__ Woh) {
  __shared__ int s_cnt[NEXP], s_off[NEXP], s_cur[NEXP];
  __shared__ int s_tn[T_TOK];
  int b = blockIdx.x;
  int tid = threadIdx.x;
  if (b == 0) {
    if (tid < NEXP) s_cnt[tid] = 0;
    for (int t = tid; t < T_TOK; t += 256) s_tn[t] = 0;
    __syncthreads();
    for (int t = tid; t < T_TOK; t += 256)
      for (int e = 0; e < NEXP; ++e)
        if (disp[t * NEXP + e] > 0.f) atomicAdd(&s_cnt[e], 1);
    __syncthreads();
    if (tid == 0) {
      int acc = 0;
      for (int e = 0; e < NEXP; ++e) { s_off[e] = acc; acc += s_cnt[e]; }
    }
    __syncthreads();
    if (tid < NEXP) {
      s_cur[tid] = s_off[tid];
      meta[tid] = s_cnt[tid];
      meta[NEXP + tid] = s_off[tid];
    }
    __syncthreads();
    for (int t = tid; t < T_TOK; t += 256)
      for (int e = 0; e < NEXP; ++e)
        if (disp[t * NEXP + e] > 0.f) {
          int p = atomicAdd(&s_cur[e], 1);
          row_token[p] = t;
          row_comb[p] = comb[t * NEXP + e];
          int sl = atomicAdd(&s_tn[t], 1);
          tok2pair[t * 2 + sl] = p;
        }
    __syncthreads();
    if (tid == 0) {
      int nt = 0;
      for (int e = 0; e < NEXP; ++e)
        for (int m0 = 0; m0 < s_cnt[e]; m0 += 128)
          meta[17 + nt++] = (e << 16) | (m0 >> 7);
      meta[16] = nt;
    }
    return;
  }
  // conversion blocks: 2048 fp32 elems each
  int idx = b - 1;
  const float* src;
  unsigned short* dst;
  size_t base;
  if (idx < 768) {                       // X: T_TOK*DIM / 2048 = 768
    src = X; dst = Xb; base = (size_t)idx * 2048;
  } else {
    idx -= 768;
    int w = idx / 9216;                  // NEXP*HDIM*DIM / 2048 = 9216 per tensor
    int off = idx % 9216;
    base = (size_t)off * 2048;
    src = (w == 0) ? Wg : (w == 1) ? Wv : Wo;
    dst = (w == 0) ? Wgh : (w == 1) ? Wvh : Woh;
  }
  size_t i = base + (size_t)tid * 8;
  float4 a = *(const float4*)(src + i);
  float4 bb = *(const float4*)(src + i + 4);
  unsigned short r[8];
  r[0]=f2bf(a.x); r[1]=f2bf(a.y); r[2]=f2bf(a.z); r[3]=f2bf(a.w);
  r[4]=f2bf(bb.x); r[5]=f2bf(bb.y); r[6]=f2bf(bb.z); r[7]=f2bf(bb.w);
  *(uint4*)(dst + i) = *(uint4*)r;
}

// ------- GEMM 1 fused: u = gelu(X@Wg^T) * (X@Wv^T) -> bf16 (P,H) -------
// WBF=1: bf16 weights (r3-proven: gv 142->98us). Strip-affinity XCD remap
// (r4-proven: FETCH 338->102MB): all m-tiles of one (e, n-strip) weight
// strip land on the same XCD, schedule-adjacent.
template<int WBF>
__global__ __launch_bounds__(256, 2) void k_gemm_gv_t(
    const unsigned short* __restrict__ Xb,  // (T_TOK, DIM) bf16
    const float* __restrict__ Wg,           // (NEXP, HDIM, DIM) fp32
    const float* __restrict__ Wv,
    const unsigned short* __restrict__ Wgh, // (NEXP, HDIM, DIM) bf16
    const unsigned short* __restrict__ Wvh,
    const int* __restrict__ meta,
    const int* __restrict__ row_token,
    unsigned short* __restrict__ ubuf)      // (MAXP, HDIM) bf16
{
  int blk = blockIdx.x;                     // 960 = 8 xcd * 3 strips * 40 tiles
  int xc = blk & 7, slot = blk >> 3;
  int nt = xc + 8 * (slot / NTILE_MAX);     // n-strip pinned to xcd
  int t  = slot % NTILE_MAX;
  if (t >= meta[16]) return;
  int tv = meta[17 + t];
  int e = tv >> 16, m0 = (tv & 0xffff) << 7;
  int cnt = meta[e], off = meta[NEXP + e];
  int n0 = nt * 128;

  __shared__ unsigned short As[128 * LDST];
  __shared__ unsigned short Bgs[128 * LDST];
  __shared__ unsigned short Bvs[128 * LDST];

  int tid = threadIdx.x;
  int wid = tid >> 6, lane = tid & 63;
  int wm = (wid >> 1) * 64, wn = (wid & 1) * 64;
  int lr = lane & 15, quad = lane >> 4;

  int a_tok[2];
#pragma unroll
  for (int r = 0; r < 2; ++r) {
    int row = (tid + 256 * r) >> 2;
    int gr = m0 + row; if (gr >= cnt) gr = cnt - 1;
    a_tok[r] = row_token[off + gr];
  }

  const float* Wgb = Wg + (size_t)e * ((size_t)HDIM * DIM);
  const float* Wvb = Wv + (size_t)e * ((size_t)HDIM * DIM);
  const unsigned short* Wghb = Wgh + (size_t)e * ((size_t)HDIM * DIM);
  const unsigned short* Wvhb = Wvh + (size_t)e * ((size_t)HDIM * DIM);

  f32x4 zero4 = {0.f, 0.f, 0.f, 0.f};
  f32x4 accg[4][4], accv[4][4];
#pragma unroll
  for (int i = 0; i < 4; ++i)
#pragma unroll
    for (int j = 0; j < 4; ++j) { accg[i][j] = zero4; accv[i][j] = zero4; }

  for (int k0 = 0; k0 < DIM; k0 += 32) {
    __syncthreads();
#pragma unroll
    for (int r = 0; r < 2; ++r) {
      int c2 = tid + 256 * r;
      int row = c2 >> 2, sub = c2 & 3;
      uint4 av = *(const uint4*)(Xb + (size_t)a_tok[r] * DIM + k0 + sub * 8);
      *(uint4*)(&As[row * LDST + sub * 8]) = av;
    }
    if constexpr (WBF) {
#pragma unroll
      for (int r = 0; r < 2; ++r) {
        int c2 = tid + 256 * r;
        int row = c2 >> 2, sub = c2 & 3;
        uint4 gv = *(const uint4*)(Wghb + (size_t)(n0 + row) * DIM + k0 + sub * 8);
        *(uint4*)(&Bgs[row * LDST + sub * 8]) = gv;
        uint4 vv = *(const uint4*)(Wvhb + (size_t)(n0 + row) * DIM + k0 + sub * 8);
        *(uint4*)(&Bvs[row * LDST + sub * 8]) = vv;
      }
    } else {
#pragma unroll
      for (int r = 0; r < 4; ++r) {
        int c2 = tid + 256 * r;
        int row = c2 >> 3, c4 = c2 & 7;
        float4 gv = *(const float4*)(Wgb + (size_t)(n0 + row) * DIM + k0 + c4 * 4);
        ushort4 gp;
        gp.x = f2bf(gv.x); gp.y = f2bf(gv.y); gp.z = f2bf(gv.z); gp.w = f2bf(gv.w);
        *(ushort4*)(&Bgs[row * LDST + c4 * 4]) = gp;
        float4 vv = *(const float4*)(Wvb + (size_t)(n0 + row) * DIM + k0 + c4 * 4);
        ushort4 vp;
        vp.x = f2bf(vv.x); vp.y = f2bf(vv.y); vp.z = f2bf(vv.z); vp.w = f2bf(vv.w);
        *(ushort4*)(&Bvs[row * LDST + c4 * 4]) = vp;
      }
    }
    __syncthreads();
    bfrag a[4], bg[4], bv[4];
#pragma unroll
    for (int i = 0; i < 4; ++i)
      a[i] = *(const bfrag*)(&As[(wm + i * 16 + lr) * LDST + quad * 8]);
#pragma unroll
    for (int j = 0; j < 4; ++j) {
      bg[j] = *(const bfrag*)(&Bgs[(wn + j * 16 + lr) * LDST + quad * 8]);
      bv[j] = *(const bfrag*)(&Bvs[(wn + j * 16 + lr) * LDST + quad * 8]);
    }
#pragma unroll
    for (int i = 0; i < 4; ++i)
#pragma unroll
      for (int j = 0; j < 4; ++j) {
        accg[i][j] = __builtin_amdgcn_mfma_f32_16x16x32_bf16(a[i], bg[j], accg[i][j], 0, 0, 0);
        accv[i][j] = __builtin_amdgcn_mfma_f32_16x16x32_bf16(a[i], bv[j], accv[i][j], 0, 0, 0);
      }
  }

  // epilogue: gelu_exact(g)*v on fp32 accumulators
#pragma unroll
  for (int i = 0; i < 4; ++i)
#pragma unroll
    for (int rg = 0; rg < 4; ++rg) {
      int gr = m0 + wm + i * 16 + quad * 4 + rg;
      if (gr < cnt) {
        size_t base = (size_t)(off + gr) * HDIM + n0 + wn;
#pragma unroll
        for (int j = 0; j < 4; ++j) {
          float g = accg[i][j][rg];
          float v = accv[i][j][rg];
          float u = 0.5f * g * (1.0f + erff(g * 0.70710678118654752f)) * v;
          ubuf[base + j * 16 + lr] = f2bf(u);
        }
      }
    }
}

// ------- GEMM 2: u @ Wo^T, split-K x4, strip-affinity remap over (nt,ks).
//         mode 0: store w-scaled partials; mode 1: atomicAdd fallback. -------
template<int WBF>
__global__ __launch_bounds__(256, 2) void k_gemm_out_t(
    const unsigned short* __restrict__ U,  // (MAXP, HDIM) bf16
    const float* __restrict__ Wo,          // (NEXP, DIM, HDIM) fp32
    const unsigned short* __restrict__ Woh,// (NEXP, DIM, HDIM) bf16
    const float* __restrict__ scale,
    const int* __restrict__ meta,
    const int* __restrict__ row_token,
    const float* __restrict__ row_comb,
    float* __restrict__ partial,           // (4, MAXP, DIM)
    float* __restrict__ out,               // (T_TOK, DIM)
    int mode)
{
  int blk = blockIdx.x;                    // 960 = 8 xcd * 3 strips * 40 tiles
  int xc = blk & 7, slot = blk >> 3;
  int sidx = xc + 8 * (slot / NTILE_MAX);  // 0..23 strip index = (nt, ks)
  int nt = sidx % 6, ks = sidx / 6;
  int t = slot % NTILE_MAX;
  if (t >= meta[16]) return;
  int tv = meta[17 + t];
  int e = tv >> 16, m0 = (tv & 0xffff) << 7;
  int cnt = meta[e], off = meta[NEXP + e];
  int n0 = nt * 128;
  int kbase = ks * (HDIM / 4);

  __shared__ unsigned short As[128 * LDST];
  __shared__ unsigned short Bs[128 * LDST];

  int tid = threadIdx.x;
  int wid = tid >> 6, lane = tid & 63;
  int wm = (wid >> 1) * 64, wn = (wid & 1) * 64;
  int lr = lane & 15, quad = lane >> 4;

  int a_grow[2];
#pragma unroll
  for (int r = 0; r < 2; ++r) {
    int row = (tid + 256 * r) >> 2;
    int gr = m0 + row; if (gr >= cnt) gr = cnt - 1;
    a_grow[r] = off + gr;
  }

  const float* Wb = Wo + (size_t)e * ((size_t)DIM * HDIM);
  const unsigned short* Wbh = Woh + (size_t)e * ((size_t)DIM * HDIM);

  f32x4 zero4 = {0.f, 0.f, 0.f, 0.f};
  f32x4 acc[4][4];
#pragma unroll
  for (int i = 0; i < 4; ++i)
#pragma unroll
    for (int j = 0; j < 4; ++j) acc[i][j] = zero4;

  for (int kk = 0; kk < HDIM / 4; kk += 32) {
    int k0 = kbase + kk;
    __syncthreads();
#pragma unroll
    for (int r = 0; r < 2; ++r) {
      int c2 = tid + 256 * r;
      int row = c2 >> 2, sub = c2 & 3;
      uint4 av = *(const uint4*)(U + (size_t)a_grow[r] * HDIM + k0 + sub * 8);
      *(uint4*)(&As[row * LDST + sub * 8]) = av;
    }
    if constexpr (WBF) {
#pragma unroll
      for (int r = 0; r < 2; ++r) {
        int c2 = tid + 256 * r;
        int row = c2 >> 2, sub = c2 & 3;
        uint4 bv = *(const uint4*)(Wbh + (size_t)(n0 + row) * HDIM + k0 + sub * 8);
        *(uint4*)(&Bs[row * LDST + sub * 8]) = bv;
      }
    } else {
#pragma unroll
      for (int r = 0; r < 4; ++r) {
        int c2 = tid + 256 * r;
        int row = c2 >> 3, c4 = c2 & 7;
        float4 bvv = *(const float4*)(Wb + (size_t)(n0 + row) * HDIM + k0 + c4 * 4);
        ushort4 bp;
        bp.x = f2bf(bvv.x); bp.y = f2bf(bvv.y); bp.z = f2bf(bvv.z); bp.w = f2bf(bvv.w);
        *(ushort4*)(&Bs[row * LDST + c4 * 4]) = bp;
      }
    }
    __syncthreads();
    bfrag a[4], b[4];
#pragma unroll
    for (int i = 0; i < 4; ++i)
      a[i] = *(const bfrag*)(&As[(wm + i * 16 + lr) * LDST + quad * 8]);
#pragma unroll
    for (int j = 0; j < 4; ++j)
      b[j] = *(const bfrag*)(&Bs[(wn + j * 16 + lr) * LDST + quad * 8]);
#pragma unroll
    for (int i = 0; i < 4; ++i)
#pragma unroll
      for (int j = 0; j < 4; ++j)
        acc[i][j] = __builtin_amdgcn_mfma_f32_16x16x32_bf16(a[i], b[j], acc[i][j], 0, 0, 0);
  }

  float sc = scale[e];
#pragma unroll
  for (int i = 0; i < 4; ++i)
#pragma unroll
    for (int rg = 0; rg < 4; ++rg) {
      int gr = m0 + wm + i * 16 + quad * 4 + rg;
      if (gr < cnt) {
        int grow = off + gr;
        float w = row_comb[grow] * sc;
        if (mode == 0) {
          float* pb = partial + ((size_t)ks * MAXP + grow) * DIM + n0 + wn;
#pragma unroll
          for (int j = 0; j < 4; ++j)
            pb[j * 16 + lr] = acc[i][j][rg] * w;
        } else {
          int tok = row_token[grow];
          float* ob = out + (size_t)tok * DIM + n0 + wn;
#pragma unroll
          for (int j = 0; j < 4; ++j)
            atomicAdd(ob + j * 16 + lr, acc[i][j][rg] * w);
        }
      }
    }
}

// ---------------- combine: out[t] = sum over 2 pairs x 4 K-splits ----------------
__global__ void k_combine(const float* __restrict__ partial,
                          const int* __restrict__ tok2pair,
                          float* __restrict__ out) {
  int idx = blockIdx.x * 256 + threadIdx.x;   // 2048 * 192 = 393216
  int t = idx / 192, d4 = idx % 192;
  int p0 = tok2pair[t * 2], p1 = tok2pair[t * 2 + 1];
  float sx = 0.f, sy = 0.f, sz = 0.f, sw = 0.f;
#pragma unroll
  for (int ks = 0; ks < 4; ++ks) {
    float4 a = *(const float4*)(partial + ((size_t)ks * MAXP + p0) * DIM + d4 * 4);
    float4 b = *(const float4*)(partial + ((size_t)ks * MAXP + p1) * DIM + d4 * 4);
    sx += a.x + b.x; sy += a.y + b.y; sz += a.z + b.z; sw += a.w + b.w;
  }
  float4 r; r.x = sx; r.y = sy; r.z = sz; r.w = sw;
  *(float4*)(out + (size_t)t * DIM + d4 * 4) = r;
}

extern "C" void kernel_launch(void* const* d_in, const int* in_sizes, int n_in,
                              void* d_out, int out_size, void* d_ws, size_t ws_size,
                              hipStream_t stream) {
  const float* tokens = (const float*)d_in[0];
  const float* disp   = (const float*)d_in[1];
  const float* comb   = (const float*)d_in[2];
  const float* Wg     = (const float*)d_in[3];
  const float* Wv     = (const float*)d_in[4];
  const float* Wo     = (const float*)d_in[5];
  const float* scale  = (const float*)d_in[6];
  float* out = (float*)d_out;

  char* ws = (char*)d_ws;
  int*   meta      = (int*)ws;                        // 57 ints
  int*   row_token = (int*)(ws + 16384);
  float* row_comb  = (float*)(ws + 32768);
  int*   tok2pair  = (int*)(ws + 49152);
  unsigned short* Xb   = (unsigned short*)(ws + (1ull << 20));          // 3 MB
  unsigned short* ubuf = (unsigned short*)(ws + (5ull << 20));          // 24 MB
  float* partial = (float*)(ws + (32ull << 20));                        // 48 MB

  // bf16 weight copies: each tensor 8*3072*768*2 B = 36 MiB.
  const size_t need_partial = (32ull << 20) + (size_t)4 * MAXP * DIM * sizeof(float); // 80 MiB
  const size_t need_full = 188ull << 20;   // 80 front + 3x36 weights
  const size_t need_mid  = 140ull << 20;   // 32 front (no partial) + 3x36

  int wbf, mode;
  unsigned short *Wgh = nullptr, *Wvh = nullptr, *Woh = nullptr;
  if (ws_size >= need_full) {
    wbf = 1; mode = 0;
    Wgh = (unsigned short*)(ws + (80ull  << 20));
    Wvh = (unsigned short*)(ws + (116ull << 20));
    Woh = (unsigned short*)(ws + (152ull << 20));
  } else if (ws_size >= need_mid) {
    wbf = 1; mode = 1;   // weights overlap partial space -> atomic combine
    Wgh = (unsigned short*)(ws + (32ull  << 20));
    Wvh = (unsigned short*)(ws + (68ull  << 20));
    Woh = (unsigned short*)(ws + (104ull << 20));
  } else {
    wbf = 0;
    mode = (ws_size >= need_partial) ? 0 : 1;
    Wgh = Wvh = Woh = (unsigned short*)Xb;  // unused by WBF=0 path
  }

  // fused routing + conversions (route block hides under conversion stream)
  int prep_grid = wbf ? (1 + 768 + 3 * 9216) : (1 + 768);
  hipLaunchKernelGGL(k_prep, dim3(prep_grid), dim3(256), 0, stream,
                     disp, comb, meta, row_comb, row_token, tok2pair,
                     tokens, Xb, Wg, Wv, Wo, Wgh, Wvh, Woh);

  if (wbf)
    hipLaunchKernelGGL(HIP_KERNEL_NAME(k_gemm_gv_t<1>), dim3(NTILE_MAX * 24), dim3(256), 0, stream,
                       Xb, Wg, Wv, Wgh, Wvh, meta, row_token, ubuf);
  else
    hipLaunchKernelGGL(HIP_KERNEL_NAME(k_gemm_gv_t<0>), dim3(NTILE_MAX * 24), dim3(256), 0, stream,
                       Xb, Wg, Wv, Wgh, Wvh, meta, row_token, ubuf);

  if (mode == 1)
    hipMemsetAsync(d_out, 0, (size_t)out_size * sizeof(float), stream);

  if (wbf)
    hipLaunchKernelGGL(HIP_KERNEL_NAME(k_gemm_out_t<1>), dim3(NTILE_MAX * 6 * 4), dim3(256), 0, stream,
                       ubuf, Wo, Woh, scale, meta, row_token, row_comb, partial, out, mode);
  else
    hipLaunchKernelGGL(HIP_KERNEL_NAME(k_gemm_out_t<0>), dim3(NTILE_MAX * 6 * 4), dim3(256), 0, stream,
                       ubuf, Wo, Woh, scale, meta, row_token, row_comb, partial, out, mode);

  if (mode == 0)
    hipLaunchKernelGGL(k_combine, dim3((T_TOK * DIM / 4) / 256), dim3(256), 0, stream,
                       partial, tok2pair, out);
}